// Round 1
// baseline (323.179 us; speedup 1.0000x reference)
//
#include <hip/hip_runtime.h>

// HONAM: B=8192, F=256, per-feature MLP 1->32->64->32, ORDER=2, OUT=1
#define B_   8192
#define F_   256
#define H1_  32
#define H2_  64
#define H3_  32
#define BR   128       // batch rows per block
#define NFC  8         // feature chunks
#define FC   (F_/NFC)  // features per block = 32

// ---------------- Kernel 1: feature nets + p1/p2 partial accumulation ----------------
// grid = (B/BR) * NFC = 64*8 = 512 blocks, 256 threads.
// thread (g,l): g = tid>>3 (0..31) owns rows r0+g*4..+3 ; l = tid&7 owns output slices.
__global__ __launch_bounds__(256, 2)
void honam_k1(const float* __restrict__ xg,
              const float* __restrict__ w1g, const float* __restrict__ b1g,
              const float* __restrict__ w2g, const float* __restrict__ b2g,
              const float* __restrict__ w3g, const float* __restrict__ b3g,
              float* __restrict__ p1ws, float* __restrict__ p2ws)
{
    __shared__ float w2s[H1_ * H2_];       // 8 KB
    __shared__ float w3s[H2_ * H3_];       // 8 KB
    __shared__ float h2t[H2_][132];        // transposed h2 [out][row], pad 132 -> 33 KB
    __shared__ float w1s[H1_], b1s[H1_], b2s[H2_], b3s[H3_];

    const int tid  = threadIdx.x;
    const int bx   = blockIdx.x;
    const int fcid = bx % NFC;
    const int bcid = bx / NFC;
    const int r0   = bcid * BR;
    const int f0   = fcid * FC;
    const int g    = tid >> 3;   // 0..31
    const int l    = tid & 7;    // 0..7

    float pacc1[4][4] = {{0.f}};
    float pacc2[4][4] = {{0.f}};

    for (int fi = 0; fi < FC; ++fi) {
        const int f = f0 + fi;
        // ---- stage weights for feature f ----
        {
            const float4* w2src = (const float4*)(w2g + (size_t)f * (H1_ * H2_));
            float4* w2dst = (float4*)w2s;
            w2dst[tid]       = w2src[tid];
            w2dst[tid + 256] = w2src[tid + 256];
            const float4* w3src = (const float4*)(w3g + (size_t)f * (H2_ * H3_));
            float4* w3dst = (float4*)w3s;
            w3dst[tid]       = w3src[tid];
            w3dst[tid + 256] = w3src[tid + 256];
            if (tid < 32)       w1s[tid]       = w1g[f * H1_ + tid];
            else if (tid < 64)  b1s[tid - 32]  = b1g[f * H1_ + (tid - 32)];
            else if (tid < 128) b2s[tid - 64]  = b2g[f * H2_ + (tid - 64)];
            else if (tid < 160) b3s[tid - 128] = b3g[f * H3_ + (tid - 128)];
        }
        // x for my 4 rows (issued before barrier to overlap latency)
        float xv[4];
#pragma unroll
        for (int rr = 0; rr < 4; ++rr)
            xv[rr] = xg[(size_t)(r0 + g * 4 + rr) * F_ + f];

        __syncthreads();

        // ---- phase 2: h1 on the fly, h2 = relu(h1 @ W2 + b2) ----
        // thread computes rows g*4..+3  x  outs l*8..+7
        float acc2[4][8];
#pragma unroll
        for (int rr = 0; rr < 4; ++rr)
#pragma unroll
            for (int oo = 0; oo < 8; ++oo)
                acc2[rr][oo] = b2s[l * 8 + oo];

#pragma unroll
        for (int k = 0; k < H1_; ++k) {
            const float w1k = w1s[k];
            const float b1k = b1s[k];
            float h1v[4];
#pragma unroll
            for (int rr = 0; rr < 4; ++rr)
                h1v[rr] = fmaxf(fmaf(xv[rr], w1k, b1k), 0.0f);
            const float4 wa = *(const float4*)&w2s[k * H2_ + l * 8];
            const float4 wb = *(const float4*)&w2s[k * H2_ + l * 8 + 4];
            const float wv[8] = {wa.x, wa.y, wa.z, wa.w, wb.x, wb.y, wb.z, wb.w};
#pragma unroll
            for (int rr = 0; rr < 4; ++rr)
#pragma unroll
                for (int oo = 0; oo < 8; ++oo)
                    acc2[rr][oo] = fmaf(h1v[rr], wv[oo], acc2[rr][oo]);
        }
        // relu + store transposed: h2t[out][row]
#pragma unroll
        for (int oo = 0; oo < 8; ++oo) {
            float4 v;
            v.x = fmaxf(acc2[0][oo], 0.f);
            v.y = fmaxf(acc2[1][oo], 0.f);
            v.z = fmaxf(acc2[2][oo], 0.f);
            v.w = fmaxf(acc2[3][oo], 0.f);
            *(float4*)&h2t[l * 8 + oo][g * 4] = v;
        }
        __syncthreads();

        // ---- phase 3: h3 = relu(h2 @ W3 + b3); accumulate p1/p2 ----
        // thread computes rows g*4..+3  x  outs l*4..+3
        float acc3[4][4];
#pragma unroll
        for (int rr = 0; rr < 4; ++rr)
#pragma unroll
            for (int oo = 0; oo < 4; ++oo)
                acc3[rr][oo] = b3s[l * 4 + oo];

#pragma unroll
        for (int k = 0; k < H2_; ++k) {
            const float4 h4 = *(const float4*)&h2t[k][g * 4];
            const float4 w4 = *(const float4*)&w3s[k * H3_ + l * 4];
            const float hv[4] = {h4.x, h4.y, h4.z, h4.w};
            const float wv[4] = {w4.x, w4.y, w4.z, w4.w};
#pragma unroll
            for (int rr = 0; rr < 4; ++rr)
#pragma unroll
                for (int oo = 0; oo < 4; ++oo)
                    acc3[rr][oo] = fmaf(hv[rr], wv[oo], acc3[rr][oo]);
        }
#pragma unroll
        for (int rr = 0; rr < 4; ++rr)
#pragma unroll
            for (int oo = 0; oo < 4; ++oo) {
                const float t = fmaxf(acc3[rr][oo], 0.f);
                pacc1[rr][oo] += t;
                pacc2[rr][oo] += t * t;
            }
        __syncthreads();
    }

    // ---- accumulate partials into global p1/p2 (8 contenders per address) ----
#pragma unroll
    for (int rr = 0; rr < 4; ++rr)
#pragma unroll
        for (int oo = 0; oo < 4; ++oo) {
            const int idx = (r0 + g * 4 + rr) * H3_ + (l * 4 + oo);
            atomicAdd(&p1ws[idx], pacc1[rr][oo]);
            atomicAdd(&p2ws[idx], pacc2[rr][oo]);
        }
}

// ---------------- Kernel 2: Newton identities + output head ----------------
// Each group of 32 lanes handles one row: val = p1*Wa + 0.5*(p1^2 - p2)*Wb, reduce, +bout.
__global__ __launch_bounds__(256)
void honam_k2(const float* __restrict__ p1ws, const float* __restrict__ p2ws,
              const float* __restrict__ woutg, const float* __restrict__ boutg,
              float* __restrict__ outg)
{
    const int tid = threadIdx.x;
    const int o   = tid & 31;
    const int r   = blockIdx.x * 8 + (tid >> 5);
    const float v1 = p1ws[r * H3_ + o];
    const float v2 = p2ws[r * H3_ + o];
    const float wa = woutg[o];
    const float wb = woutg[H3_ + o];
    float val = v1 * wa + 0.5f * (v1 * v1 - v2) * wb;
#pragma unroll
    for (int off = 16; off > 0; off >>= 1)
        val += __shfl_down(val, off, 32);
    if (o == 0) outg[r] = val + boutg[0];
}

extern "C" void kernel_launch(void* const* d_in, const int* in_sizes, int n_in,
                              void* d_out, int out_size, void* d_ws, size_t ws_size,
                              hipStream_t stream)
{
    const float* xg   = (const float*)d_in[0];
    const float* w1g  = (const float*)d_in[1];
    const float* b1g  = (const float*)d_in[2];
    const float* w2g  = (const float*)d_in[3];
    const float* b2g  = (const float*)d_in[4];
    const float* w3g  = (const float*)d_in[5];
    const float* b3g  = (const float*)d_in[6];
    const float* woutg = (const float*)d_in[7];
    const float* boutg = (const float*)d_in[8];
    float* outg = (float*)d_out;

    float* p1ws = (float*)d_ws;
    float* p2ws = p1ws + (size_t)B_ * H3_;

    // zero the p1/p2 accumulators every call (deterministic; ws is poisoned once)
    hipMemsetAsync(d_ws, 0, (size_t)B_ * H3_ * 2 * sizeof(float), stream);

    honam_k1<<<dim3((B_ / BR) * NFC), dim3(256), 0, stream>>>(
        xg, w1g, b1g, w2g, b2g, w3g, b3g, p1ws, p2ws);

    honam_k2<<<dim3(B_ / 8), dim3(256), 0, stream>>>(p1ws, p2ws, woutg, boutg, outg);
}

// Round 3
// 92.833 us; speedup vs baseline: 3.4813x; 3.4813x over previous
//
#include <hip/hip_runtime.h>
#include <hip/hip_bf16.h>

#define B_   8192
#define F_   256
#define NFC  16            // feature chunks (blocks along F)
#define NF   (F_/NFC)      // 16 features per block
#define RPB  256           // rows per block
#define NSUB 4             // 4 subtiles of 64 rows

typedef __attribute__((ext_vector_type(8))) short v8s;   // bf16x8 A/B frag (4 VGPR)
typedef __attribute__((ext_vector_type(4))) float v4f;   // f32x4 C/D frag
typedef __attribute__((ext_vector_type(4))) unsigned int v4u;

static __device__ __forceinline__ unsigned short f2bf(float f) {
    __hip_bfloat16 h = __float2bfloat16(f);
    return __builtin_bit_cast(unsigned short, h);
}
static __device__ __forceinline__ unsigned int pack2bf(float a, float b) {
    return (unsigned int)f2bf(a) | ((unsigned int)f2bf(b) << 16);
}

// ---------------- prep: pack W2/W3 into MFMA fragment order, bf16 ----------------
// Frags 0..3: W2 tile n as A-fragment for h2^T = W2^T @ h1^T:
//   lane(c,g) elem j  ->  W2[k = g*8+j][unit = n*16+c]
// Frags 4+kk*2+n2: W3 as B-fragment for t = h2 @ W3, with the u-map chosen to
// match GEMM1's D-fragment register order:
//   lane(c,g) elem j  ->  W3[u = (kk*2+(j>>2))*16 + g*4 + (j&3)][n2*16+c]
__global__ __launch_bounds__(256)
void honam_prep(const float* __restrict__ w2g, const float* __restrict__ w3g,
                unsigned short* __restrict__ wf)
{
    const int f   = blockIdx.x;
    const int tid = threadIdx.x;
    const float* w2 = w2g + (size_t)f * 2048;
    const float* w3 = w3g + (size_t)f * 2048;
    unsigned short* dst = wf + (size_t)f * 4096;
    for (int i = tid; i < 4096; i += 256) {
        const int frag = i >> 9;
        const int l    = (i >> 3) & 63;
        const int j    = i & 7;
        const int c    = l & 15;
        const int g    = l >> 4;
        float v;
        if (frag < 4) {
            v = w2[(g * 8 + j) * 64 + frag * 16 + c];            // W2[k][n*16+c]
        } else {
            const int kk = (frag - 4) >> 1;
            const int n2 = (frag - 4) & 1;
            const int u  = (kk * 2 + (j >> 2)) * 16 + g * 4 + (j & 3);
            v = w3[u * 32 + n2 * 16 + c];                        // W3[u][n2*16+c]
        }
        dst[i] = f2bf(v);
    }
}

// ---------------- Kernel 1: MFMA feature nets + p1/p2, register-only dataflow ----------------
__global__ __launch_bounds__(256, 2)
void honam_k1(const float* __restrict__ xg,
              const float* __restrict__ w1g, const float* __restrict__ b1g,
              const float* __restrict__ b2g, const float* __restrict__ b3g,
              const unsigned short* __restrict__ wfg,
              float* __restrict__ p1ws, float* __restrict__ p2ws)
{
    __shared__ short wlds[8 * 512] __attribute__((aligned(16)));  // 8 frags x 1KB = 8KB

    const int tid  = threadIdx.x;
    const int wave = tid >> 6;
    const int lane = tid & 63;
    const int c16  = lane & 15;
    const int g4   = lane >> 4;

    const int bx = blockIdx.x;
    const int rb = bx >> 4;          // 0..31
    const int fc = bx & 15;          // 0..15
    const int r0 = rb * RPB;
    const int f0 = fc * NF;

    float pacc1[NSUB][2][4];
    float pacc2[NSUB][2][4];
#pragma unroll
    for (int s = 0; s < NSUB; ++s)
#pragma unroll
        for (int n2 = 0; n2 < 2; ++n2)
#pragma unroll
            for (int j = 0; j < 4; ++j) { pacc1[s][n2][j] = 0.f; pacc2[s][n2][j] = 0.f; }

    // prologue: prefetch feature f0's two frags for this wave
    v8s st0 = *(const v8s*)&wfg[(size_t)f0 * 4096 + (2 * wave) * 512 + lane * 8];
    v8s st1 = *(const v8s*)&wfg[(size_t)f0 * 4096 + (2 * wave + 1) * 512 + lane * 8];

    for (int fi = 0; fi < NF; ++fi) {
        const int f = f0 + fi;
        // stage this feature's frags to LDS
        *(v8s*)&wlds[(2 * wave) * 512 + lane * 8]     = st0;
        *(v8s*)&wlds[(2 * wave + 1) * 512 + lane * 8] = st1;
        // prefetch next feature (a full compute phase of latency hiding)
        if (fi + 1 < NF) {
            st0 = *(const v8s*)&wfg[(size_t)(f + 1) * 4096 + (2 * wave) * 512 + lane * 8];
            st1 = *(const v8s*)&wfg[(size_t)(f + 1) * 4096 + (2 * wave + 1) * 512 + lane * 8];
        }
        __syncthreads();
        v8s wfr[8];
#pragma unroll
        for (int fr = 0; fr < 8; ++fr)
            wfr[fr] = *(const v8s*)&wlds[fr * 512 + lane * 8];
        __syncthreads();   // wlds free for next iteration

        // per-feature scalars (f32, L1/L2-cached)
        const float4 w1a = *(const float4*)&w1g[f * 32 + g4 * 8];
        const float4 w1b = *(const float4*)&w1g[f * 32 + g4 * 8 + 4];
        const float4 b1a = *(const float4*)&b1g[f * 32 + g4 * 8];
        const float4 b1b = *(const float4*)&b1g[f * 32 + g4 * 8 + 4];
        const float w1v[8] = {w1a.x, w1a.y, w1a.z, w1a.w, w1b.x, w1b.y, w1b.z, w1b.w};
        const float b1v[8] = {b1a.x, b1a.y, b1a.z, b1a.w, b1b.x, b1b.y, b1b.z, b1b.w};
        // b2 as per-reg C-in for swapped GEMM1: reg j <-> unit n*16+g4*4+j
        float4 b2c[4];
#pragma unroll
        for (int n = 0; n < 4; ++n)
            b2c[n] = *(const float4*)&b2g[f * 64 + n * 16 + g4 * 4];
        float b3v[2];
#pragma unroll
        for (int n = 0; n < 2; ++n) b3v[n] = b3g[f * 32 + n * 16 + c16];

#pragma unroll
        for (int sub = 0; sub < NSUB; ++sub) {
            const int mrow = r0 + sub * 64 + wave * 16 + c16;
            const float xm = xg[(size_t)mrow * F_ + f];
            // h1 as B-frag of GEMM1: lane(c16,g4) elem j = h1[m=c16][k=g4*8+j]
            unsigned h1p[4];
#pragma unroll
            for (int jj = 0; jj < 4; ++jj) {
                const float e0 = fmaxf(fmaf(xm, w1v[2 * jj],     b1v[2 * jj]),     0.f);
                const float e1 = fmaxf(fmaf(xm, w1v[2 * jj + 1], b1v[2 * jj + 1]), 0.f);
                h1p[jj] = pack2bf(e0, e1);
            }
            const v8s bh1 = __builtin_bit_cast(v8s, (v4u){h1p[0], h1p[1], h1p[2], h1p[3]});

            // GEMM1 (swapped): h2^T = W2^T @ h1^T + b2
            // D reg j = h2[m=c16][unit n*16+g4*4+j]
            v4f acc2[4];
#pragma unroll
            for (int n = 0; n < 4; ++n)
                acc2[n] = __builtin_amdgcn_mfma_f32_16x16x32_bf16(
                    wfr[n], bh1, (v4f){b2c[n].x, b2c[n].y, b2c[n].z, b2c[n].w}, 0, 0, 0);

            // relu + pack: D-frags ARE GEMM2's A-frags under the prep-side u-map
            unsigned q[8];
#pragma unroll
            for (int n = 0; n < 4; ++n) {
                q[2 * n]     = pack2bf(fmaxf(acc2[n][0], 0.f), fmaxf(acc2[n][1], 0.f));
                q[2 * n + 1] = pack2bf(fmaxf(acc2[n][2], 0.f), fmaxf(acc2[n][3], 0.f));
            }
            const v8s a2k0 = __builtin_bit_cast(v8s, (v4u){q[0], q[1], q[2], q[3]});
            const v8s a2k1 = __builtin_bit_cast(v8s, (v4u){q[4], q[5], q[6], q[7]});

            // GEMM2: t = relu(h2 @ W3 + b3)
            v4f acc3[2];
#pragma unroll
            for (int n2 = 0; n2 < 2; ++n2) {
                acc3[n2] = __builtin_amdgcn_mfma_f32_16x16x32_bf16(
                    a2k0, wfr[4 + n2], (v4f){b3v[n2], b3v[n2], b3v[n2], b3v[n2]}, 0, 0, 0);
                acc3[n2] = __builtin_amdgcn_mfma_f32_16x16x32_bf16(
                    a2k1, wfr[6 + n2], acc3[n2], 0, 0, 0);
            }
#pragma unroll
            for (int n2 = 0; n2 < 2; ++n2)
#pragma unroll
                for (int j = 0; j < 4; ++j) {
                    const float t = fmaxf(acc3[n2][j], 0.f);
                    pacc1[sub][n2][j] += t;
                    pacc2[sub][n2][j] = fmaf(t, t, pacc2[sub][n2][j]);
                }
        }
    }

    // accumulate partial power sums (NFC=16 contenders per address)
#pragma unroll
    for (int sub = 0; sub < NSUB; ++sub)
#pragma unroll
        for (int n2 = 0; n2 < 2; ++n2)
#pragma unroll
            for (int j = 0; j < 4; ++j) {
                const int row = r0 + sub * 64 + wave * 16 + g4 * 4 + j;
                const int col = n2 * 16 + c16;
                atomicAdd(&p1ws[row * 32 + col], pacc1[sub][n2][j]);
                atomicAdd(&p2ws[row * 32 + col], pacc2[sub][n2][j]);
            }
}

// ---------------- Kernel 2: Newton identities + output head ----------------
__global__ __launch_bounds__(256)
void honam_k2(const float* __restrict__ p1ws, const float* __restrict__ p2ws,
              const float* __restrict__ woutg, const float* __restrict__ boutg,
              float* __restrict__ outg)
{
    const int tid = threadIdx.x;
    const int o   = tid & 31;
    const int r   = blockIdx.x * 8 + (tid >> 5);
    const float v1 = p1ws[r * 32 + o];
    const float v2 = p2ws[r * 32 + o];
    const float wa = woutg[o];
    const float wb = woutg[32 + o];
    float val = v1 * wa + 0.5f * (v1 * v1 - v2) * wb;
#pragma unroll
    for (int off = 16; off > 0; off >>= 1)
        val += __shfl_down(val, off, 32);
    if (o == 0) outg[r] = val + boutg[0];
}

extern "C" void kernel_launch(void* const* d_in, const int* in_sizes, int n_in,
                              void* d_out, int out_size, void* d_ws, size_t ws_size,
                              hipStream_t stream)
{
    const float* xg    = (const float*)d_in[0];
    const float* w1g   = (const float*)d_in[1];
    const float* b1g   = (const float*)d_in[2];
    const float* w2g   = (const float*)d_in[3];
    const float* b2g   = (const float*)d_in[4];
    const float* w3g   = (const float*)d_in[5];
    const float* b3g   = (const float*)d_in[6];
    const float* woutg = (const float*)d_in[7];
    const float* boutg = (const float*)d_in[8];
    float* outg = (float*)d_out;

    float* p1ws = (float*)d_ws;                                     // 1 MB
    float* p2ws = p1ws + (size_t)B_ * 32;                           // 1 MB
    unsigned short* wf = (unsigned short*)(p2ws + (size_t)B_ * 32); // 2 MB packed weights

    hipMemsetAsync(d_ws, 0, (size_t)B_ * 32 * 2 * sizeof(float), stream);

    honam_prep<<<dim3(F_), dim3(256), 0, stream>>>(w2g, w3g, wf);

    honam_k1<<<dim3((B_ / RPB) * NFC), dim3(256), 0, stream>>>(
        xg, w1g, b1g, b2g, b3g, wf, p1ws, p2ws);

    honam_k2<<<dim3(B_ / 8), dim3(256), 0, stream>>>(p1ws, p2ws, woutg, boutg, outg);
}

// Round 4
// 68.584 us; speedup vs baseline: 4.7122x; 1.3536x over previous
//
#include <hip/hip_runtime.h>
#include <hip/hip_bf16.h>

#define B_   8192
#define F_   256
#define NFC  16            // feature chunks (blocks along F)
#define NF   (F_/NFC)      // 16 features per block
#define RPB  128           // rows per block
#define NSUB 2             // 2 subtiles of 64 rows

typedef __attribute__((ext_vector_type(8))) short v8s;   // bf16x8 A/B frag (4 VGPR)
typedef __attribute__((ext_vector_type(4))) float v4f;   // f32x4 C/D frag
typedef __attribute__((ext_vector_type(4))) unsigned int v4u;

static __device__ __forceinline__ unsigned short f2bf(float f) {
    __hip_bfloat16 h = __float2bfloat16(f);
    return __builtin_bit_cast(unsigned short, h);
}
static __device__ __forceinline__ unsigned int pack2bf(float a, float b) {
    return (unsigned int)f2bf(a) | ((unsigned int)f2bf(b) << 16);
}

// ---------------- prep: pack W2/W3 into MFMA fragment order, bf16 ----------------
// Frags 0..3: W2 tile n as A-fragment for h2^T = W2^T @ h1^T:
//   lane(c,g) elem j  ->  W2[k = g*8+j][unit = n*16+c]
// Frags 4+kk*2+n2: W3 as B-fragment for t = h2 @ W3, u-map matching GEMM1's D order:
//   lane(c,g) elem j  ->  W3[u = (kk*2+(j>>2))*16 + g*4 + (j&3)][n2*16+c]
__global__ __launch_bounds__(256)
void honam_prep(const float* __restrict__ w2g, const float* __restrict__ w3g,
                unsigned short* __restrict__ wf)
{
    const int f   = blockIdx.x;
    const int tid = threadIdx.x;
    const float* w2 = w2g + (size_t)f * 2048;
    const float* w3 = w3g + (size_t)f * 2048;
    unsigned short* dst = wf + (size_t)f * 4096;
    for (int i = tid; i < 4096; i += 256) {
        const int frag = i >> 9;
        const int l    = (i >> 3) & 63;
        const int j    = i & 7;
        const int c    = l & 15;
        const int g    = l >> 4;
        float v;
        if (frag < 4) {
            v = w2[(g * 8 + j) * 64 + frag * 16 + c];            // W2[k][n*16+c]
        } else {
            const int kk = (frag - 4) >> 1;
            const int n2 = (frag - 4) & 1;
            const int u  = (kk * 2 + (j >> 2)) * 16 + g * 4 + (j & 3);
            v = w3[u * 32 + n2 * 16 + c];                        // W3[u][n2*16+c]
        }
        dst[i] = f2bf(v);
    }
}

// ---------------- Kernel 1: MFMA feature nets + p1/p2, barrier-free main loop ----------------
__global__ __launch_bounds__(256, 4)
void honam_k1(const float* __restrict__ xg,
              const float* __restrict__ w1g, const float* __restrict__ b1g,
              const float* __restrict__ b2g, const float* __restrict__ b3g,
              const unsigned short* __restrict__ wfg,
              float* __restrict__ p1ws, float* __restrict__ p2ws)
{
    __shared__ float xs[NF][RPB];     // x-tile transposed: 16 features x 128 rows = 8KB

    const int tid  = threadIdx.x;
    const int wave = tid >> 6;
    const int lane = tid & 63;
    const int c16  = lane & 15;
    const int g4   = lane >> 4;

    const int bx = blockIdx.x;
    const int rb = bx >> 4;          // 0..63
    const int fc = bx & 15;          // 0..15
    const int r0 = rb * RPB;
    const int f0 = fc * NF;

    // ---- stage x-tile once, coalesced, stored transposed ----
    {
        const int row  = tid >> 1;   // 0..127
        const int half = tid & 1;    // 0..1
        const float4 va = *(const float4*)&xg[(size_t)(r0 + row) * F_ + f0 + half * 8];
        const float4 vb = *(const float4*)&xg[(size_t)(r0 + row) * F_ + f0 + half * 8 + 4];
        const int fb = half * 8;
        xs[fb + 0][row] = va.x; xs[fb + 1][row] = va.y;
        xs[fb + 2][row] = va.z; xs[fb + 3][row] = va.w;
        xs[fb + 4][row] = vb.x; xs[fb + 5][row] = vb.y;
        xs[fb + 6][row] = vb.z; xs[fb + 7][row] = vb.w;
    }
    __syncthreads();   // the only barrier in this kernel

    float pacc1[NSUB][2][4];
    float pacc2[NSUB][2][4];
#pragma unroll
    for (int s = 0; s < NSUB; ++s)
#pragma unroll
        for (int n2 = 0; n2 < 2; ++n2)
#pragma unroll
            for (int j = 0; j < 4; ++j) { pacc1[s][n2][j] = 0.f; pacc2[s][n2][j] = 0.f; }

    for (int fi = 0; fi < NF; ++fi) {
        const int f = f0 + fi;
        // weight frags straight from global (L1/L2-resident, coalesced 16B/lane)
        const v8s* wp = (const v8s*)(wfg + (size_t)f * 4096);
        v8s wfr[8];
#pragma unroll
        for (int fr = 0; fr < 8; ++fr)
            wfr[fr] = wp[fr * 64 + lane];

        // per-feature scalars (f32, L1-cached)
        const float4 w1a = *(const float4*)&w1g[f * 32 + g4 * 8];
        const float4 w1b = *(const float4*)&w1g[f * 32 + g4 * 8 + 4];
        const float4 b1a = *(const float4*)&b1g[f * 32 + g4 * 8];
        const float4 b1b = *(const float4*)&b1g[f * 32 + g4 * 8 + 4];
        const float w1v[8] = {w1a.x, w1a.y, w1a.z, w1a.w, w1b.x, w1b.y, w1b.z, w1b.w};
        const float b1v[8] = {b1a.x, b1a.y, b1a.z, b1a.w, b1b.x, b1b.y, b1b.z, b1b.w};
        // b2 as per-reg C-in for swapped GEMM1: reg j <-> unit n*16+g4*4+j
        float4 b2c[4];
#pragma unroll
        for (int n = 0; n < 4; ++n)
            b2c[n] = *(const float4*)&b2g[f * 64 + n * 16 + g4 * 4];
        float b3v[2];
#pragma unroll
        for (int n = 0; n < 2; ++n) b3v[n] = b3g[f * 32 + n * 16 + c16];

#pragma unroll
        for (int sub = 0; sub < NSUB; ++sub) {
            const float xm = xs[fi][sub * 64 + wave * 16 + c16];
            // h1 as B-frag of GEMM1: lane(c16,g4) elem j = h1[m=c16][k=g4*8+j]
            unsigned h1p[4];
#pragma unroll
            for (int jj = 0; jj < 4; ++jj) {
                const float e0 = fmaxf(fmaf(xm, w1v[2 * jj],     b1v[2 * jj]),     0.f);
                const float e1 = fmaxf(fmaf(xm, w1v[2 * jj + 1], b1v[2 * jj + 1]), 0.f);
                h1p[jj] = pack2bf(e0, e1);
            }
            const v8s bh1 = __builtin_bit_cast(v8s, (v4u){h1p[0], h1p[1], h1p[2], h1p[3]});

            // GEMM1 (swapped): h2^T = W2^T @ h1^T + b2 ; D reg j = h2[m=c16][n*16+g4*4+j]
            v4f acc2[4];
#pragma unroll
            for (int n = 0; n < 4; ++n)
                acc2[n] = __builtin_amdgcn_mfma_f32_16x16x32_bf16(
                    wfr[n], bh1, (v4f){b2c[n].x, b2c[n].y, b2c[n].z, b2c[n].w}, 0, 0, 0);

            // relu + pack: D-frags ARE GEMM2's A-frags under the prep-side u-map
            unsigned q[8];
#pragma unroll
            for (int n = 0; n < 4; ++n) {
                q[2 * n]     = pack2bf(fmaxf(acc2[n][0], 0.f), fmaxf(acc2[n][1], 0.f));
                q[2 * n + 1] = pack2bf(fmaxf(acc2[n][2], 0.f), fmaxf(acc2[n][3], 0.f));
            }
            const v8s a2k0 = __builtin_bit_cast(v8s, (v4u){q[0], q[1], q[2], q[3]});
            const v8s a2k1 = __builtin_bit_cast(v8s, (v4u){q[4], q[5], q[6], q[7]});

            // GEMM2: t = relu(h2 @ W3 + b3)
            v4f acc3[2];
#pragma unroll
            for (int n2 = 0; n2 < 2; ++n2) {
                acc3[n2] = __builtin_amdgcn_mfma_f32_16x16x32_bf16(
                    a2k0, wfr[4 + n2], (v4f){b3v[n2], b3v[n2], b3v[n2], b3v[n2]}, 0, 0, 0);
                acc3[n2] = __builtin_amdgcn_mfma_f32_16x16x32_bf16(
                    a2k1, wfr[6 + n2], acc3[n2], 0, 0, 0);
            }
#pragma unroll
            for (int n2 = 0; n2 < 2; ++n2)
#pragma unroll
                for (int j = 0; j < 4; ++j) {
                    const float t = fmaxf(acc3[n2][j], 0.f);
                    pacc1[sub][n2][j] += t;
                    pacc2[sub][n2][j] = fmaf(t, t, pacc2[sub][n2][j]);
                }
        }
    }

    // accumulate partial power sums (NFC=16 contenders per address)
#pragma unroll
    for (int sub = 0; sub < NSUB; ++sub)
#pragma unroll
        for (int n2 = 0; n2 < 2; ++n2)
#pragma unroll
            for (int j = 0; j < 4; ++j) {
                const int row = r0 + sub * 64 + wave * 16 + g4 * 4 + j;
                const int col = n2 * 16 + c16;
                atomicAdd(&p1ws[row * 32 + col], pacc1[sub][n2][j]);
                atomicAdd(&p2ws[row * 32 + col], pacc2[sub][n2][j]);
            }
}

// ---------------- Kernel 2: Newton identities + output head ----------------
__global__ __launch_bounds__(256)
void honam_k2(const float* __restrict__ p1ws, const float* __restrict__ p2ws,
              const float* __restrict__ woutg, const float* __restrict__ boutg,
              float* __restrict__ outg)
{
    const int tid = threadIdx.x;
    const int o   = tid & 31;
    const int r   = blockIdx.x * 8 + (tid >> 5);
    const float v1 = p1ws[r * 32 + o];
    const float v2 = p2ws[r * 32 + o];
    const float wa = woutg[o];
    const float wb = woutg[32 + o];
    float val = v1 * wa + 0.5f * (v1 * v1 - v2) * wb;
#pragma unroll
    for (int off = 16; off > 0; off >>= 1)
        val += __shfl_down(val, off, 32);
    if (o == 0) outg[r] = val + boutg[0];
}

extern "C" void kernel_launch(void* const* d_in, const int* in_sizes, int n_in,
                              void* d_out, int out_size, void* d_ws, size_t ws_size,
                              hipStream_t stream)
{
    const float* xg    = (const float*)d_in[0];
    const float* w1g   = (const float*)d_in[1];
    const float* b1g   = (const float*)d_in[2];
    const float* w2g   = (const float*)d_in[3];
    const float* b2g   = (const float*)d_in[4];
    const float* w3g   = (const float*)d_in[5];
    const float* b3g   = (const float*)d_in[6];
    const float* woutg = (const float*)d_in[7];
    const float* boutg = (const float*)d_in[8];
    float* outg = (float*)d_out;

    float* p1ws = (float*)d_ws;                                     // 1 MB
    float* p2ws = p1ws + (size_t)B_ * 32;                           // 1 MB
    unsigned short* wf = (unsigned short*)(p2ws + (size_t)B_ * 32); // 2 MB packed weights

    hipMemsetAsync(d_ws, 0, (size_t)B_ * 32 * 2 * sizeof(float), stream);

    honam_prep<<<dim3(F_), dim3(256), 0, stream>>>(w2g, w3g, wf);

    honam_k1<<<dim3((B_ / RPB) * NFC), dim3(256), 0, stream>>>(
        xg, w1g, b1g, b2g, b3g, wf, p1ws, p2ws);

    honam_k2<<<dim3(B_ / 8), dim3(256), 0, stream>>>(p1ws, p2ws, woutg, boutg, outg);
}